// Round 8
// baseline (268.260 us; speedup 1.0000x reference)
//
#include <hip/hip_runtime.h>

#define N_FEAT_IN 256
#define N_HID 256
#define N_OUT 128

using f32x4 = __attribute__((ext_vector_type(4))) float;
using bf16x8 = __attribute__((ext_vector_type(8))) short;

__device__ inline unsigned short bf16_rne(float f) {
    unsigned u = __builtin_bit_cast(unsigned, f);
    unsigned r = u + 0x7FFFu + ((u >> 16) & 1u);
    return (unsigned short)(r >> 16);
}
__device__ inline float bf16_to_f(unsigned short h) {
    unsigned u = ((unsigned)h) << 16;
    return __builtin_bit_cast(float, u);
}

// ---------------------------------------------------------------------------
// Edge dtype probe (int64 vs int32 edge_index layout)
// ---------------------------------------------------------------------------
__global__ void detect_i64_kernel(const int* __restrict__ edges, int* __restrict__ flag) {
    __shared__ int s[256];
    int tid = threadIdx.x;
    int zeros = 0;
    for (int i = tid; i < 2048; i += 256) zeros += (edges[2 * i + 1] == 0) ? 1 : 0;
    s[tid] = zeros;
    __syncthreads();
    for (int off = 128; off; off >>= 1) {
        if (tid < off) s[tid] += s[tid + off];
        __syncthreads();
    }
    if (tid == 0) flag[0] = (s[0] > 1900) ? 1 : 0;
}

// convert + count fused: one pass over edges
__global__ void convert_count_kernel(const void* __restrict__ edges, int E,
                                     const int* __restrict__ flag,
                                     int* __restrict__ src, int* __restrict__ dst,
                                     int* __restrict__ cnt) {
    int e = blockIdx.x * blockDim.x + threadIdx.x;
    if (e >= E) return;
    int s, d;
    if (flag[0]) {
        const long long* p = (const long long*)edges;
        s = (int)p[e];
        d = (int)p[(size_t)E + e];
    } else {
        const int* p = (const int*)edges;
        s = p[e];
        d = p[(size_t)E + e];
    }
    src[e] = s;
    dst[e] = d;
    atomicAdd(&cnt[d], 1);
}

// ---------------------------------------------------------------------------
// Hierarchical exclusive scan (block scan also emits dinv from cnt)
// ---------------------------------------------------------------------------
__global__ __launch_bounds__(256) void scan_block_kernel(
    const int* __restrict__ cnt, int Nn, int* __restrict__ rowp, int* __restrict__ bsum,
    float* __restrict__ dinv) {
    __shared__ int sd[256];
    const int tid = threadIdx.x;
    const int i = blockIdx.x * 256 + tid;
    const int v = (i < Nn) ? cnt[i] : 0;
    if (i < Nn) dinv[i] = rsqrtf((float)(v + 1));
    sd[tid] = v;
    __syncthreads();
    for (int off = 1; off < 256; off <<= 1) {
        int t = (tid >= off) ? sd[tid - off] : 0;
        __syncthreads();
        sd[tid] += t;
        __syncthreads();
    }
    if (i < Nn) rowp[i] = sd[tid] - v;
    if (tid == 255) bsum[blockIdx.x] = sd[255];
}

__global__ __launch_bounds__(256) void scan_top_kernel(
    int* __restrict__ bsum, int Nb, int* __restrict__ rowp, int Nn) {
    __shared__ int sd[256];
    const int tid = threadIdx.x;
    const int v = (tid < Nb) ? bsum[tid] : 0;
    sd[tid] = v;
    __syncthreads();
    for (int off = 1; off < 256; off <<= 1) {
        int t = (tid >= off) ? sd[tid - off] : 0;
        __syncthreads();
        sd[tid] += t;
        __syncthreads();
    }
    if (tid < Nb) bsum[tid] = sd[tid] - v;
    if (tid == 255) rowp[Nn] = sd[255];
}

__global__ __launch_bounds__(256) void scan_add_kernel(
    const int* __restrict__ bsum, int Nn, int* __restrict__ rowp, int* __restrict__ cursor) {
    const int i = blockIdx.x * 256 + threadIdx.x;
    if (i < Nn) {
        const int r = rowp[i] + bsum[i >> 8];
        rowp[i] = r;
        cursor[i] = r;
    }
}

// Packed CSR fill: one 8B scatter per edge (col + nrm in one int2)
__global__ void fill_kernel(const int* __restrict__ src, const int* __restrict__ dst, int E,
                            const float* __restrict__ dinv, int* __restrict__ cursor,
                            int2* __restrict__ ce) {
    int e = blockIdx.x * blockDim.x + threadIdx.x;
    if (e >= E) return;
    int s = src[e], d = dst[e];
    int pos = atomicAdd(&cursor[d], 1);
    float w = dinv[s] * dinv[d];
    ce[pos] = make_int2(s, __builtin_bit_cast(int, w));
}

// ---------------------------------------------------------------------------
// Split fp32 -> (hi, lo) bf16 pair. hi = rne(f), lo = rne(f - hi).
// ---------------------------------------------------------------------------
__global__ __launch_bounds__(256) void split_kernel(
    const float* __restrict__ in, int n4,
    unsigned short* __restrict__ hi, unsigned short* __restrict__ lo) {
    int i = blockIdx.x * 256 + threadIdx.x;
    if (i >= n4) return;
    float4 v = ((const float4*)in)[i];
    ushort4 h, l;
    h.x = bf16_rne(v.x); l.x = bf16_rne(v.x - bf16_to_f(h.x));
    h.y = bf16_rne(v.y); l.y = bf16_rne(v.y - bf16_to_f(h.y));
    h.z = bf16_rne(v.z); l.z = bf16_rne(v.z - bf16_to_f(h.z));
    h.w = bf16_rne(v.w); l.w = bf16_rne(v.w - bf16_to_f(h.w));
    ((ushort4*)hi)[i] = h;
    ((ushort4*)lo)[i] = l;
}

// Split + transpose weights: W[K][N] -> T_hi/T_lo [N][K]
__global__ __launch_bounds__(256) void splitT_kernel(
    const float* __restrict__ W, int K, int N,
    unsigned short* __restrict__ thi, unsigned short* __restrict__ tlo) {
    int idx = blockIdx.x * 256 + threadIdx.x;
    if (idx >= K * N) return;
    int k = idx / N, n = idx - k * N;
    float f = W[idx];
    unsigned short h = bf16_rne(f);
    unsigned short l = bf16_rne(f - bf16_to_f(h));
    thi[(size_t)n * K + k] = h;
    tlo[(size_t)n * K + k] = l;
}

// ---------------------------------------------------------------------------
// Split-bf16 MFMA GEMM: C[M,N] = (Ah+Al)[M,K] @ (Bh+Bl)^T[N,K]^T.
// 3-term: hi*hi + lo*hi + hi*lo. Output: bf16 (rounded) gather table.
// 128x128 tile, 4 waves 2x2 (64x64/wave), BK=32, 16x16x32 bf16 MFMA.
// ---------------------------------------------------------------------------
__global__ __launch_bounds__(256) void gemm_mfma_kernel(
    const unsigned short* __restrict__ Ah, const unsigned short* __restrict__ Al,
    const unsigned short* __restrict__ Bh, const unsigned short* __restrict__ Bl,
    unsigned short* __restrict__ C, int M, int N, int K) {
    __shared__ char lds[4 * 128 * 64];
    char* As_h = lds;
    char* As_l = lds + 8192;
    char* Bs_h = lds + 16384;
    char* Bs_l = lds + 24576;

    const int tid = threadIdx.x;
    const int lane = tid & 63;
    const int wv = tid >> 6;
    const int wrow = (wv >> 1) * 64;
    const int wcol = (wv & 1) * 64;

    const int srow = tid >> 1;   // 0..127
    const int shalf = tid & 1;   // k-offset 0/16

    const long arow_g = (long)blockIdx.y * 128 + srow;
    const bool aval = arow_g < M;
    const int bcol_g = blockIdx.x * 128 + srow;  // N % 128 == 0

    const size_t a_base = (size_t)(aval ? arow_g : 0) * K + shalf * 16;
    const size_t b_base = (size_t)bcol_g * K + shalf * 16;

    const int sw = ((srow >> 1) & 3) << 4;
    const int w0 = (srow * 64 + shalf * 32) ^ sw;
    const int w1 = (srow * 64 + shalf * 32 + 16) ^ sw;

    int ra[4], rb[4];
#pragma unroll
    for (int m = 0; m < 4; m++) {
        int r = wrow + m * 16 + (lane & 15);
        ra[m] = (r * 64 + (lane >> 4) * 16) ^ (((r >> 1) & 3) << 4);
        int c = wcol + m * 16 + (lane & 15);
        rb[m] = (c * 64 + (lane >> 4) * 16) ^ (((c >> 1) & 3) << 4);
    }

    f32x4 acc[4][4] = {};
    const bf16x8 zero8 = {0, 0, 0, 0, 0, 0, 0, 0};

    const int nkt = K >> 5;
    for (int kt = 0; kt < nkt; kt++) {
        const int kb = kt * 32;
        bf16x8 vah0 = zero8, vah1 = zero8, val0 = zero8, val1 = zero8;
        if (aval) {
            vah0 = *(const bf16x8*)(Ah + a_base + kb);
            vah1 = *(const bf16x8*)(Ah + a_base + kb + 8);
            val0 = *(const bf16x8*)(Al + a_base + kb);
            val1 = *(const bf16x8*)(Al + a_base + kb + 8);
        }
        bf16x8 vbh0 = *(const bf16x8*)(Bh + b_base + kb);
        bf16x8 vbh1 = *(const bf16x8*)(Bh + b_base + kb + 8);
        bf16x8 vbl0 = *(const bf16x8*)(Bl + b_base + kb);
        bf16x8 vbl1 = *(const bf16x8*)(Bl + b_base + kb + 8);
        __syncthreads();
        *(bf16x8*)(As_h + w0) = vah0;  *(bf16x8*)(As_h + w1) = vah1;
        *(bf16x8*)(As_l + w0) = val0;  *(bf16x8*)(As_l + w1) = val1;
        *(bf16x8*)(Bs_h + w0) = vbh0;  *(bf16x8*)(Bs_h + w1) = vbh1;
        *(bf16x8*)(Bs_l + w0) = vbl0;  *(bf16x8*)(Bs_l + w1) = vbl1;
        __syncthreads();
        bf16x8 ah[4], al[4], bh[4], bl[4];
#pragma unroll
        for (int m = 0; m < 4; m++) {
            ah[m] = *(const bf16x8*)(As_h + ra[m]);
            al[m] = *(const bf16x8*)(As_l + ra[m]);
            bh[m] = *(const bf16x8*)(Bs_h + rb[m]);
            bl[m] = *(const bf16x8*)(Bs_l + rb[m]);
        }
#pragma unroll
        for (int m = 0; m < 4; m++)
#pragma unroll
            for (int n = 0; n < 4; n++) {
                acc[m][n] = __builtin_amdgcn_mfma_f32_16x16x32_bf16(ah[m], bh[n], acc[m][n], 0, 0, 0);
                acc[m][n] = __builtin_amdgcn_mfma_f32_16x16x32_bf16(al[m], bh[n], acc[m][n], 0, 0, 0);
                acc[m][n] = __builtin_amdgcn_mfma_f32_16x16x32_bf16(ah[m], bl[n], acc[m][n], 0, 0, 0);
            }
    }

    const int c0 = blockIdx.x * 128 + wcol + (lane & 15);
    const long r0 = (long)blockIdx.y * 128 + wrow + (lane >> 4) * 4;
#pragma unroll
    for (int m = 0; m < 4; m++)
#pragma unroll
        for (int j = 0; j < 4; j++) {
            long r = r0 + m * 16 + j;
            if (r < M) {
#pragma unroll
                for (int n = 0; n < 4; n++)
                    C[(size_t)r * N + c0 + n * 16] = bf16_rne(acc[m][n][j]);
            }
        }
}

// ---------------------------------------------------------------------------
// CSR aggregation over a bf16 gather table, wave-per-node, fp32 accumulate.
// Packed CSR (int2 col+nrm); indices broadcast to SGPR via readlane; gathers
// issued 8 deep for MLP (~4KB outstanding per wave).
// ---------------------------------------------------------------------------
template <int C, bool RELU, bool SPLIT>
__global__ __launch_bounds__(256) void agg_kernel(
    const unsigned short* __restrict__ h, const int* __restrict__ rowp,
    const int2* __restrict__ ce,
    const float* __restrict__ dinv, const float* __restrict__ bias,
    float* __restrict__ out,
    unsigned short* __restrict__ ohi, unsigned short* __restrict__ olo, int Nn) {
    constexpr int VEC = C / 64;
    static_assert(VEC == 2 || VEC == 4, "C must be 128 or 256");
    const int lane = threadIdx.x & 63;
    const int wv = threadIdx.x >> 6;
    const int node0 = blockIdx.x * 4 + wv;
    if (node0 >= Nn) return;
    const int node = __builtin_amdgcn_readfirstlane(node0);
    const float di = dinv[node];
    const int coff = lane * VEC;
    const unsigned short* __restrict__ hc = h + coff;
    float acc[VEC];

    auto loadrow = [&](int row, float v[VEC]) {
        const unsigned short* r = hc + (size_t)row * C;
        if constexpr (VEC == 4) {
            ushort4 t = *(const ushort4*)r;
            v[0] = bf16_to_f(t.x); v[1] = bf16_to_f(t.y);
            v[2] = bf16_to_f(t.z); v[3] = bf16_to_f(t.w);
        } else {
            ushort2 t = *(const ushort2*)r;
            v[0] = bf16_to_f(t.x); v[1] = bf16_to_f(t.y);
        }
    };

    {
        float v[VEC];
        loadrow(node, v);
#pragma unroll
        for (int j = 0; j < VEC; j++) acc[j] = di * di * v[j];
    }

    const int s = rowp[node];
    const int e = rowp[node + 1];
    for (int base = s; base < e; base += 64) {
        const int m = min(64, e - base);
        int myc = 0, myn = 0;
        if (lane < m) {
            int2 p = ce[base + lane];
            myc = p.x;
            myn = p.y;
        }
        int j = 0;
        for (; j + 8 <= m; j += 8) {
            int cc[8];
            float ww[8];
#pragma unroll
            for (int t = 0; t < 8; t++) {
                cc[t] = __builtin_amdgcn_readlane(myc, j + t);
                ww[t] = __builtin_bit_cast(float, __builtin_amdgcn_readlane(myn, j + t));
            }
            float v0[VEC], v1[VEC], v2[VEC], v3[VEC], v4[VEC], v5[VEC], v6[VEC], v7[VEC];
            loadrow(cc[0], v0);
            loadrow(cc[1], v1);
            loadrow(cc[2], v2);
            loadrow(cc[3], v3);
            loadrow(cc[4], v4);
            loadrow(cc[5], v5);
            loadrow(cc[6], v6);
            loadrow(cc[7], v7);
#pragma unroll
            for (int q = 0; q < VEC; q++)
                acc[q] += ww[0] * v0[q] + ww[1] * v1[q] + ww[2] * v2[q] + ww[3] * v3[q] +
                          ww[4] * v4[q] + ww[5] * v5[q] + ww[6] * v6[q] + ww[7] * v7[q];
        }
        for (; j + 4 <= m; j += 4) {
            const int c0 = __builtin_amdgcn_readlane(myc, j);
            const int c1 = __builtin_amdgcn_readlane(myc, j + 1);
            const int c2 = __builtin_amdgcn_readlane(myc, j + 2);
            const int c3 = __builtin_amdgcn_readlane(myc, j + 3);
            const float w0 = __builtin_bit_cast(float, __builtin_amdgcn_readlane(myn, j));
            const float w1 = __builtin_bit_cast(float, __builtin_amdgcn_readlane(myn, j + 1));
            const float w2 = __builtin_bit_cast(float, __builtin_amdgcn_readlane(myn, j + 2));
            const float w3 = __builtin_bit_cast(float, __builtin_amdgcn_readlane(myn, j + 3));
            float v0[VEC], v1[VEC], v2[VEC], v3[VEC];
            loadrow(c0, v0);
            loadrow(c1, v1);
            loadrow(c2, v2);
            loadrow(c3, v3);
#pragma unroll
            for (int q = 0; q < VEC; q++)
                acc[q] += w0 * v0[q] + w1 * v1[q] + w2 * v2[q] + w3 * v3[q];
        }
        for (; j < m; ++j) {
            const int c0 = __builtin_amdgcn_readlane(myc, j);
            const float w0 = __builtin_bit_cast(float, __builtin_amdgcn_readlane(myn, j));
            float v0[VEC];
            loadrow(c0, v0);
#pragma unroll
            for (int q = 0; q < VEC; q++) acc[q] += w0 * v0[q];
        }
    }

    {
        const float* bv = bias + coff;
#pragma unroll
        for (int j = 0; j < VEC; j++) {
            acc[j] += bv[j];
            if (RELU) acc[j] = fmaxf(acc[j], 0.f);
        }
    }
    if constexpr (SPLIT) {
        if constexpr (VEC == 4) {
            ushort4 hh, ll;
            hh.x = bf16_rne(acc[0]); ll.x = bf16_rne(acc[0] - bf16_to_f(hh.x));
            hh.y = bf16_rne(acc[1]); ll.y = bf16_rne(acc[1] - bf16_to_f(hh.y));
            hh.z = bf16_rne(acc[2]); ll.z = bf16_rne(acc[2] - bf16_to_f(hh.z));
            hh.w = bf16_rne(acc[3]); ll.w = bf16_rne(acc[3] - bf16_to_f(hh.w));
            *(ushort4*)(ohi + (size_t)node * C + coff) = hh;
            *(ushort4*)(olo + (size_t)node * C + coff) = ll;
        } else {
            ushort2 hh, ll;
            hh.x = bf16_rne(acc[0]); ll.x = bf16_rne(acc[0] - bf16_to_f(hh.x));
            hh.y = bf16_rne(acc[1]); ll.y = bf16_rne(acc[1] - bf16_to_f(hh.y));
            *(ushort2*)(ohi + (size_t)node * C + coff) = hh;
            *(ushort2*)(olo + (size_t)node * C + coff) = ll;
        }
    } else {
        float* o = out + (size_t)node * C + coff;
        if constexpr (VEC == 4) {
            *(float4*)o = make_float4(acc[0], acc[1], acc[2], acc[3]);
        } else {
            *(float2*)o = make_float2(acc[0], acc[1]);
        }
    }
}

extern "C" void kernel_launch(void* const* d_in, const int* in_sizes, int n_in,
                              void* d_out, int out_size, void* d_ws, size_t ws_size,
                              hipStream_t stream) {
    const float* x = (const float*)d_in[0];
    const void* edges = d_in[1];
    const float* W1 = (const float*)d_in[2];
    const float* b1 = (const float*)d_in[3];
    const float* W2 = (const float*)d_in[4];
    const float* b2 = (const float*)d_in[5];
    float* out = (float*)d_out;

    const int Nn = in_sizes[0] / N_FEAT_IN;  // 50000
    const int E = in_sizes[1] / 2;           // 800000

    char* w = (char*)d_ws;
    size_t off = 0;
    auto alloc = [&](size_t bytes) -> void* {
        void* p = (void*)(w + off);
        off += (bytes + 255) & ~(size_t)255;
        return p;
    };
    int* flag = (int*)alloc(sizeof(int));
    int* srcI = (int*)alloc((size_t)E * 4);
    int* dstI = (int*)alloc((size_t)E * 4);
    int* cnt = (int*)alloc((size_t)Nn * 4);
    int* rowp = (int*)alloc(((size_t)Nn + 1) * 4);
    int* cursor = (int*)alloc((size_t)Nn * 4);
    int* bsum = (int*)alloc(1024 * 4);
    int2* ce = (int2*)alloc((size_t)E * 8);  // packed (col, nrm)
    float* dinv = (float*)alloc((size_t)Nn * 4);
    unsigned short* xhi = (unsigned short*)alloc((size_t)Nn * N_FEAT_IN * 2);
    unsigned short* xlo = (unsigned short*)alloc((size_t)Nn * N_FEAT_IN * 2);
    unsigned short* w1hi = (unsigned short*)alloc((size_t)N_FEAT_IN * N_HID * 2);
    unsigned short* w1lo = (unsigned short*)alloc((size_t)N_FEAT_IN * N_HID * 2);
    unsigned short* w2hi = (unsigned short*)alloc((size_t)N_HID * N_OUT * 2);
    unsigned short* w2lo = (unsigned short*)alloc((size_t)N_HID * N_OUT * 2);
    unsigned short* h = (unsigned short*)alloc((size_t)Nn * N_HID * 2);  // bf16 h1, then h2
    // a1 splits alias x splits: agg1 writes them only after gemm1's last read of x*.
    unsigned short* a1hi = xhi;
    unsigned short* a1lo = xlo;

    hipMemsetAsync(cnt, 0, (size_t)Nn * 4, stream);
    detect_i64_kernel<<<1, 256, 0, stream>>>((const int*)edges, flag);
    const int eb = (E + 255) / 256;
    convert_count_kernel<<<eb, 256, 0, stream>>>(edges, E, flag, srcI, dstI, cnt);
    const int nb = (Nn + 255) / 256;
    scan_block_kernel<<<nb, 256, 0, stream>>>(cnt, Nn, rowp, bsum, dinv);
    scan_top_kernel<<<1, 256, 0, stream>>>(bsum, nb, rowp, Nn);
    scan_add_kernel<<<nb, 256, 0, stream>>>(bsum, Nn, rowp, cursor);
    fill_kernel<<<eb, 256, 0, stream>>>(srcI, dstI, E, dinv, cursor, ce);

    // Precision splits
    const int n4x = Nn * N_FEAT_IN / 4;
    split_kernel<<<(n4x + 255) / 256, 256, 0, stream>>>(x, n4x, xhi, xlo);
    splitT_kernel<<<(N_FEAT_IN * N_HID + 255) / 256, 256, 0, stream>>>(W1, N_FEAT_IN, N_HID, w1hi, w1lo);
    splitT_kernel<<<(N_HID * N_OUT + 255) / 256, 256, 0, stream>>>(W2, N_HID, N_OUT, w2hi, w2lo);

    // Layer 1: h(bf16) = x @ W1 ; a1(split) = relu(Agg(h) + b1)
    dim3 g1(N_HID / 128, (Nn + 127) / 128);
    gemm_mfma_kernel<<<g1, 256, 0, stream>>>(xhi, xlo, w1hi, w1lo, h, Nn, N_HID, N_FEAT_IN);
    agg_kernel<N_HID, true, true><<<(Nn + 3) / 4, 256, 0, stream>>>(
        h, rowp, ce, dinv, b1, nullptr, a1hi, a1lo, Nn);

    // Layer 2: h2(bf16) = a1 @ W2 (reuse h); out = Agg(h2) + b2
    dim3 g2(N_OUT / 128, (Nn + 127) / 128);
    gemm_mfma_kernel<<<g2, 256, 0, stream>>>(a1hi, a1lo, w2hi, w2lo, h, Nn, N_OUT, N_HID);
    agg_kernel<N_OUT, false, false><<<(Nn + 3) / 4, 256, 0, stream>>>(
        h, rowp, ce, dinv, b2, out, nullptr, nullptr, Nn);
}

// Round 9
// 250.177 us; speedup vs baseline: 1.0723x; 1.0723x over previous
//
#include <hip/hip_runtime.h>

#define N_FEAT_IN 256
#define N_HID 256
#define N_OUT 128

using f32x4 = __attribute__((ext_vector_type(4))) float;
using bf16x8 = __attribute__((ext_vector_type(8))) short;

__device__ inline unsigned short bf16_rne(float f) {
    unsigned u = __builtin_bit_cast(unsigned, f);
    unsigned r = u + 0x7FFFu + ((u >> 16) & 1u);
    return (unsigned short)(r >> 16);
}
__device__ inline float bf16_to_f(unsigned short h) {
    unsigned u = ((unsigned)h) << 16;
    return __builtin_bit_cast(float, u);
}

// ---------------------------------------------------------------------------
// Edge dtype probe (int64 vs int32 edge_index layout)
// ---------------------------------------------------------------------------
__global__ void detect_i64_kernel(const int* __restrict__ edges, int* __restrict__ flag) {
    __shared__ int s[256];
    int tid = threadIdx.x;
    int zeros = 0;
    for (int i = tid; i < 2048; i += 256) zeros += (edges[2 * i + 1] == 0) ? 1 : 0;
    s[tid] = zeros;
    __syncthreads();
    for (int off = 128; off; off >>= 1) {
        if (tid < off) s[tid] += s[tid + off];
        __syncthreads();
    }
    if (tid == 0) flag[0] = (s[0] > 1900) ? 1 : 0;
}

// count in-degrees straight from edge_index
__global__ void count_kernel(const void* __restrict__ edges, int E,
                             const int* __restrict__ flag, int* __restrict__ cnt) {
    int e = blockIdx.x * blockDim.x + threadIdx.x;
    if (e >= E) return;
    int d;
    if (flag[0]) {
        d = (int)((const long long*)edges)[(size_t)E + e];
    } else {
        d = ((const int*)edges)[(size_t)E + e];
    }
    atomicAdd(&cnt[d], 1);
}

// ---------------------------------------------------------------------------
// Hierarchical exclusive scan (block scan also emits dinv from cnt)
// ---------------------------------------------------------------------------
__global__ __launch_bounds__(256) void scan_block_kernel(
    const int* __restrict__ cnt, int Nn, int* __restrict__ rowp, int* __restrict__ bsum,
    float* __restrict__ dinv) {
    __shared__ int sd[256];
    const int tid = threadIdx.x;
    const int i = blockIdx.x * 256 + tid;
    const int v = (i < Nn) ? cnt[i] : 0;
    if (i < Nn) dinv[i] = rsqrtf((float)(v + 1));
    sd[tid] = v;
    __syncthreads();
    for (int off = 1; off < 256; off <<= 1) {
        int t = (tid >= off) ? sd[tid - off] : 0;
        __syncthreads();
        sd[tid] += t;
        __syncthreads();
    }
    if (i < Nn) rowp[i] = sd[tid] - v;
    if (tid == 255) bsum[blockIdx.x] = sd[255];
}

__global__ __launch_bounds__(256) void scan_top_kernel(
    int* __restrict__ bsum, int Nb, int* __restrict__ rowp, int Nn) {
    __shared__ int sd[256];
    const int tid = threadIdx.x;
    const int v = (tid < Nb) ? bsum[tid] : 0;
    sd[tid] = v;
    __syncthreads();
    for (int off = 1; off < 256; off <<= 1) {
        int t = (tid >= off) ? sd[tid - off] : 0;
        __syncthreads();
        sd[tid] += t;
        __syncthreads();
    }
    if (tid < Nb) bsum[tid] = sd[tid] - v;
    if (tid == 255) rowp[Nn] = sd[255];
}

__global__ __launch_bounds__(256) void scan_add_kernel(
    const int* __restrict__ bsum, int Nn, int* __restrict__ rowp, int* __restrict__ cursor) {
    const int i = blockIdx.x * 256 + threadIdx.x;
    if (i < Nn) {
        const int r = rowp[i] + bsum[i >> 8];
        rowp[i] = r;
        cursor[i] = r;
    }
}

// Packed CSR fill straight from edge_index: one 8B scatter per edge
__global__ void fill_kernel(const void* __restrict__ edges, int E,
                            const int* __restrict__ flag,
                            const float* __restrict__ dinv, int* __restrict__ cursor,
                            int2* __restrict__ ce) {
    int e = blockIdx.x * blockDim.x + threadIdx.x;
    if (e >= E) return;
    int s, d;
    if (flag[0]) {
        const long long* p = (const long long*)edges;
        s = (int)p[e];
        d = (int)p[(size_t)E + e];
    } else {
        const int* p = (const int*)edges;
        s = p[e];
        d = p[(size_t)E + e];
    }
    int pos = atomicAdd(&cursor[d], 1);
    float w = dinv[s] * dinv[d];
    ce[pos] = make_int2(s, __builtin_bit_cast(int, w));
}

// Split + transpose weights: W[K][N] -> T_hi/T_lo [N][K]
__global__ __launch_bounds__(256) void splitT_kernel(
    const float* __restrict__ W, int K, int N,
    unsigned short* __restrict__ thi, unsigned short* __restrict__ tlo) {
    int idx = blockIdx.x * 256 + threadIdx.x;
    if (idx >= K * N) return;
    int k = idx / N, n = idx - k * N;
    float f = W[idx];
    unsigned short h = bf16_rne(f);
    unsigned short l = bf16_rne(f - bf16_to_f(h));
    thi[(size_t)n * K + k] = h;
    tlo[(size_t)n * K + k] = l;
}

// ---------------------------------------------------------------------------
// Split-bf16 MFMA GEMM, A supplied as fp32 (split fused into staging):
// C[M,N](bf16) = A[M,K](f32) @ (Bh+Bl)^T[N,K]^T via hi*hi + lo*hi + hi*lo.
// 128x128 tile, 4 waves 2x2, BK=32, 16x16x32 bf16 MFMA.
// ---------------------------------------------------------------------------
__global__ __launch_bounds__(256) void gemm_mfma_f32a_kernel(
    const float* __restrict__ Af,
    const unsigned short* __restrict__ Bh, const unsigned short* __restrict__ Bl,
    unsigned short* __restrict__ C, int M, int N, int K) {
    __shared__ char lds[4 * 128 * 64];
    char* As_h = lds;
    char* As_l = lds + 8192;
    char* Bs_h = lds + 16384;
    char* Bs_l = lds + 24576;

    const int tid = threadIdx.x;
    const int lane = tid & 63;
    const int wv = tid >> 6;
    const int wrow = (wv >> 1) * 64;
    const int wcol = (wv & 1) * 64;

    const int srow = tid >> 1;
    const int shalf = tid & 1;

    const long arow_g = (long)blockIdx.y * 128 + srow;
    const bool aval = arow_g < M;
    const int bcol_g = blockIdx.x * 128 + srow;

    const size_t a_base = (size_t)(aval ? arow_g : 0) * K + shalf * 16;
    const size_t b_base = (size_t)bcol_g * K + shalf * 16;

    const int sw = ((srow >> 1) & 3) << 4;
    const int w0 = (srow * 64 + shalf * 32) ^ sw;
    const int w1 = (srow * 64 + shalf * 32 + 16) ^ sw;

    int ra[4], rb[4];
#pragma unroll
    for (int m = 0; m < 4; m++) {
        int r = wrow + m * 16 + (lane & 15);
        ra[m] = (r * 64 + (lane >> 4) * 16) ^ (((r >> 1) & 3) << 4);
        int c = wcol + m * 16 + (lane & 15);
        rb[m] = (c * 64 + (lane >> 4) * 16) ^ (((c >> 1) & 3) << 4);
    }

    f32x4 acc[4][4] = {};

    const int nkt = K >> 5;
    for (int kt = 0; kt < nkt; kt++) {
        const int kb = kt * 32;
        float fa[16];
#pragma unroll
        for (int i = 0; i < 16; i++) fa[i] = 0.f;
        if (aval) {
#pragma unroll
            for (int i = 0; i < 4; i++) {
                float4 f = *(const float4*)(Af + a_base + kb + i * 4);
                fa[i * 4 + 0] = f.x; fa[i * 4 + 1] = f.y;
                fa[i * 4 + 2] = f.z; fa[i * 4 + 3] = f.w;
            }
        }
        bf16x8 vah0, vah1, val0, val1;
#pragma unroll
        for (int i = 0; i < 8; i++) {
            unsigned short hh = bf16_rne(fa[i]);
            unsigned short ll = bf16_rne(fa[i] - bf16_to_f(hh));
            vah0[i] = (short)hh; val0[i] = (short)ll;
            unsigned short hh1 = bf16_rne(fa[8 + i]);
            unsigned short ll1 = bf16_rne(fa[8 + i] - bf16_to_f(hh1));
            vah1[i] = (short)hh1; val1[i] = (short)ll1;
        }
        bf16x8 vbh0 = *(const bf16x8*)(Bh + b_base + kb);
        bf16x8 vbh1 = *(const bf16x8*)(Bh + b_base + kb + 8);
        bf16x8 vbl0 = *(const bf16x8*)(Bl + b_base + kb);
        bf16x8 vbl1 = *(const bf16x8*)(Bl + b_base + kb + 8);
        __syncthreads();
        *(bf16x8*)(As_h + w0) = vah0;  *(bf16x8*)(As_h + w1) = vah1;
        *(bf16x8*)(As_l + w0) = val0;  *(bf16x8*)(As_l + w1) = val1;
        *(bf16x8*)(Bs_h + w0) = vbh0;  *(bf16x8*)(Bs_h + w1) = vbh1;
        *(bf16x8*)(Bs_l + w0) = vbl0;  *(bf16x8*)(Bs_l + w1) = vbl1;
        __syncthreads();
        bf16x8 ah[4], al[4], bh[4], bl[4];
#pragma unroll
        for (int m = 0; m < 4; m++) {
            ah[m] = *(const bf16x8*)(As_h + ra[m]);
            al[m] = *(const bf16x8*)(As_l + ra[m]);
            bh[m] = *(const bf16x8*)(Bs_h + rb[m]);
            bl[m] = *(const bf16x8*)(Bs_l + rb[m]);
        }
#pragma unroll
        for (int m = 0; m < 4; m++)
#pragma unroll
            for (int n = 0; n < 4; n++) {
                acc[m][n] = __builtin_amdgcn_mfma_f32_16x16x32_bf16(ah[m], bh[n], acc[m][n], 0, 0, 0);
                acc[m][n] = __builtin_amdgcn_mfma_f32_16x16x32_bf16(al[m], bh[n], acc[m][n], 0, 0, 0);
                acc[m][n] = __builtin_amdgcn_mfma_f32_16x16x32_bf16(ah[m], bl[n], acc[m][n], 0, 0, 0);
            }
    }

    const int c0 = blockIdx.x * 128 + wcol + (lane & 15);
    const long r0 = (long)blockIdx.y * 128 + wrow + (lane >> 4) * 4;
#pragma unroll
    for (int m = 0; m < 4; m++)
#pragma unroll
        for (int j = 0; j < 4; j++) {
            long r = r0 + m * 16 + j;
            if (r < M) {
#pragma unroll
                for (int n = 0; n < 4; n++)
                    C[(size_t)r * N + c0 + n * 16] = bf16_rne(acc[m][n][j]);
            }
        }
}

// ---------------------------------------------------------------------------
// Split-bf16 MFMA GEMM, A supplied as bf16 hi/lo pair (layer 2)
// ---------------------------------------------------------------------------
__global__ __launch_bounds__(256) void gemm_mfma_kernel(
    const unsigned short* __restrict__ Ah, const unsigned short* __restrict__ Al,
    const unsigned short* __restrict__ Bh, const unsigned short* __restrict__ Bl,
    unsigned short* __restrict__ C, int M, int N, int K) {
    __shared__ char lds[4 * 128 * 64];
    char* As_h = lds;
    char* As_l = lds + 8192;
    char* Bs_h = lds + 16384;
    char* Bs_l = lds + 24576;

    const int tid = threadIdx.x;
    const int lane = tid & 63;
    const int wv = tid >> 6;
    const int wrow = (wv >> 1) * 64;
    const int wcol = (wv & 1) * 64;

    const int srow = tid >> 1;
    const int shalf = tid & 1;

    const long arow_g = (long)blockIdx.y * 128 + srow;
    const bool aval = arow_g < M;
    const int bcol_g = blockIdx.x * 128 + srow;

    const size_t a_base = (size_t)(aval ? arow_g : 0) * K + shalf * 16;
    const size_t b_base = (size_t)bcol_g * K + shalf * 16;

    const int sw = ((srow >> 1) & 3) << 4;
    const int w0 = (srow * 64 + shalf * 32) ^ sw;
    const int w1 = (srow * 64 + shalf * 32 + 16) ^ sw;

    int ra[4], rb[4];
#pragma unroll
    for (int m = 0; m < 4; m++) {
        int r = wrow + m * 16 + (lane & 15);
        ra[m] = (r * 64 + (lane >> 4) * 16) ^ (((r >> 1) & 3) << 4);
        int c = wcol + m * 16 + (lane & 15);
        rb[m] = (c * 64 + (lane >> 4) * 16) ^ (((c >> 1) & 3) << 4);
    }

    f32x4 acc[4][4] = {};
    const bf16x8 zero8 = {0, 0, 0, 0, 0, 0, 0, 0};

    const int nkt = K >> 5;
    for (int kt = 0; kt < nkt; kt++) {
        const int kb = kt * 32;
        bf16x8 vah0 = zero8, vah1 = zero8, val0 = zero8, val1 = zero8;
        if (aval) {
            vah0 = *(const bf16x8*)(Ah + a_base + kb);
            vah1 = *(const bf16x8*)(Ah + a_base + kb + 8);
            val0 = *(const bf16x8*)(Al + a_base + kb);
            val1 = *(const bf16x8*)(Al + a_base + kb + 8);
        }
        bf16x8 vbh0 = *(const bf16x8*)(Bh + b_base + kb);
        bf16x8 vbh1 = *(const bf16x8*)(Bh + b_base + kb + 8);
        bf16x8 vbl0 = *(const bf16x8*)(Bl + b_base + kb);
        bf16x8 vbl1 = *(const bf16x8*)(Bl + b_base + kb + 8);
        __syncthreads();
        *(bf16x8*)(As_h + w0) = vah0;  *(bf16x8*)(As_h + w1) = vah1;
        *(bf16x8*)(As_l + w0) = val0;  *(bf16x8*)(As_l + w1) = val1;
        *(bf16x8*)(Bs_h + w0) = vbh0;  *(bf16x8*)(Bs_h + w1) = vbh1;
        *(bf16x8*)(Bs_l + w0) = vbl0;  *(bf16x8*)(Bs_l + w1) = vbl1;
        __syncthreads();
        bf16x8 ah[4], al[4], bh[4], bl[4];
#pragma unroll
        for (int m = 0; m < 4; m++) {
            ah[m] = *(const bf16x8*)(As_h + ra[m]);
            al[m] = *(const bf16x8*)(As_l + ra[m]);
            bh[m] = *(const bf16x8*)(Bs_h + rb[m]);
            bl[m] = *(const bf16x8*)(Bs_l + rb[m]);
        }
#pragma unroll
        for (int m = 0; m < 4; m++)
#pragma unroll
            for (int n = 0; n < 4; n++) {
                acc[m][n] = __builtin_amdgcn_mfma_f32_16x16x32_bf16(ah[m], bh[n], acc[m][n], 0, 0, 0);
                acc[m][n] = __builtin_amdgcn_mfma_f32_16x16x32_bf16(al[m], bh[n], acc[m][n], 0, 0, 0);
                acc[m][n] = __builtin_amdgcn_mfma_f32_16x16x32_bf16(ah[m], bl[n], acc[m][n], 0, 0, 0);
            }
    }

    const int c0 = blockIdx.x * 128 + wcol + (lane & 15);
    const long r0 = (long)blockIdx.y * 128 + wrow + (lane >> 4) * 4;
#pragma unroll
    for (int m = 0; m < 4; m++)
#pragma unroll
        for (int j = 0; j < 4; j++) {
            long r = r0 + m * 16 + j;
            if (r < M) {
#pragma unroll
                for (int n = 0; n < 4; n++)
                    C[(size_t)r * N + c0 + n * 16] = bf16_rne(acc[m][n][j]);
            }
        }
}

// ---------------------------------------------------------------------------
// CSR aggregation over a bf16 gather table, wave-per-node, fp32 accumulate.
// Packed CSR (int2 col+nrm); indices broadcast to SGPR via readlane; gathers
// issued 4 deep (round-7 measured-best form; 8-deep regressed: VGPR 16->28).
// ---------------------------------------------------------------------------
template <int C, bool RELU, bool SPLIT>
__global__ __launch_bounds__(256) void agg_kernel(
    const unsigned short* __restrict__ h, const int* __restrict__ rowp,
    const int2* __restrict__ ce,
    const float* __restrict__ dinv, const float* __restrict__ bias,
    float* __restrict__ out,
    unsigned short* __restrict__ ohi, unsigned short* __restrict__ olo, int Nn) {
    constexpr int VEC = C / 64;
    static_assert(VEC == 2 || VEC == 4, "C must be 128 or 256");
    const int lane = threadIdx.x & 63;
    const int wv = threadIdx.x >> 6;
    const int node0 = blockIdx.x * 4 + wv;
    if (node0 >= Nn) return;
    const int node = __builtin_amdgcn_readfirstlane(node0);
    const float di = dinv[node];
    const int coff = lane * VEC;
    const unsigned short* __restrict__ hc = h + coff;
    float acc[VEC];

    auto loadrow = [&](int row, float v[VEC]) {
        const unsigned short* r = hc + (size_t)row * C;
        if constexpr (VEC == 4) {
            ushort4 t = *(const ushort4*)r;
            v[0] = bf16_to_f(t.x); v[1] = bf16_to_f(t.y);
            v[2] = bf16_to_f(t.z); v[3] = bf16_to_f(t.w);
        } else {
            ushort2 t = *(const ushort2*)r;
            v[0] = bf16_to_f(t.x); v[1] = bf16_to_f(t.y);
        }
    };

    {
        float v[VEC];
        loadrow(node, v);
#pragma unroll
        for (int j = 0; j < VEC; j++) acc[j] = di * di * v[j];
    }

    const int s = rowp[node];
    const int e = rowp[node + 1];
    for (int base = s; base < e; base += 64) {
        const int m = min(64, e - base);
        int myc = 0, myn = 0;
        if (lane < m) {
            int2 p = ce[base + lane];
            myc = p.x;
            myn = p.y;
        }
        int j = 0;
        for (; j + 4 <= m; j += 4) {
            const int c0 = __builtin_amdgcn_readlane(myc, j);
            const int c1 = __builtin_amdgcn_readlane(myc, j + 1);
            const int c2 = __builtin_amdgcn_readlane(myc, j + 2);
            const int c3 = __builtin_amdgcn_readlane(myc, j + 3);
            const float w0 = __builtin_bit_cast(float, __builtin_amdgcn_readlane(myn, j));
            const float w1 = __builtin_bit_cast(float, __builtin_amdgcn_readlane(myn, j + 1));
            const float w2 = __builtin_bit_cast(float, __builtin_amdgcn_readlane(myn, j + 2));
            const float w3 = __builtin_bit_cast(float, __builtin_amdgcn_readlane(myn, j + 3));
            float v0[VEC], v1[VEC], v2[VEC], v3[VEC];
            loadrow(c0, v0);
            loadrow(c1, v1);
            loadrow(c2, v2);
            loadrow(c3, v3);
#pragma unroll
            for (int q = 0; q < VEC; q++)
                acc[q] += w0 * v0[q] + w1 * v1[q] + w2 * v2[q] + w3 * v3[q];
        }
        for (; j < m; ++j) {
            const int c0 = __builtin_amdgcn_readlane(myc, j);
            const float w0 = __builtin_bit_cast(float, __builtin_amdgcn_readlane(myn, j));
            float v0[VEC];
            loadrow(c0, v0);
#pragma unroll
            for (int q = 0; q < VEC; q++) acc[q] += w0 * v0[q];
        }
    }

    {
        const float* bv = bias + coff;
#pragma unroll
        for (int j = 0; j < VEC; j++) {
            acc[j] += bv[j];
            if (RELU) acc[j] = fmaxf(acc[j], 0.f);
        }
    }
    if constexpr (SPLIT) {
        if constexpr (VEC == 4) {
            ushort4 hh, ll;
            hh.x = bf16_rne(acc[0]); ll.x = bf16_rne(acc[0] - bf16_to_f(hh.x));
            hh.y = bf16_rne(acc[1]); ll.y = bf16_rne(acc[1] - bf16_to_f(hh.y));
            hh.z = bf16_rne(acc[2]); ll.z = bf16_rne(acc[2] - bf16_to_f(hh.z));
            hh.w = bf16_rne(acc[3]); ll.w = bf16_rne(acc[3] - bf16_to_f(hh.w));
            *(ushort4*)(ohi + (size_t)node * C + coff) = hh;
            *(ushort4*)(olo + (size_t)node * C + coff) = ll;
        } else {
            ushort2 hh, ll;
            hh.x = bf16_rne(acc[0]); ll.x = bf16_rne(acc[0] - bf16_to_f(hh.x));
            hh.y = bf16_rne(acc[1]); ll.y = bf16_rne(acc[1] - bf16_to_f(hh.y));
            *(ushort2*)(ohi + (size_t)node * C + coff) = hh;
            *(ushort2*)(olo + (size_t)node * C + coff) = ll;
        }
    } else {
        float* o = out + (size_t)node * C + coff;
        if constexpr (VEC == 4) {
            *(float4*)o = make_float4(acc[0], acc[1], acc[2], acc[3]);
        } else {
            *(float2*)o = make_float2(acc[0], acc[1]);
        }
    }
}

extern "C" void kernel_launch(void* const* d_in, const int* in_sizes, int n_in,
                              void* d_out, int out_size, void* d_ws, size_t ws_size,
                              hipStream_t stream) {
    const float* x = (const float*)d_in[0];
    const void* edges = d_in[1];
    const float* W1 = (const float*)d_in[2];
    const float* b1 = (const float*)d_in[3];
    const float* W2 = (const float*)d_in[4];
    const float* b2 = (const float*)d_in[5];
    float* out = (float*)d_out;

    const int Nn = in_sizes[0] / N_FEAT_IN;  // 50000
    const int E = in_sizes[1] / 2;           // 800000

    char* w = (char*)d_ws;
    size_t off = 0;
    auto alloc = [&](size_t bytes) -> void* {
        void* p = (void*)(w + off);
        off += (bytes + 255) & ~(size_t)255;
        return p;
    };
    int* flag = (int*)alloc(sizeof(int));
    int* cnt = (int*)alloc((size_t)Nn * 4);
    int* rowp = (int*)alloc(((size_t)Nn + 1) * 4);
    int* cursor = (int*)alloc((size_t)Nn * 4);
    int* bsum = (int*)alloc(1024 * 4);
    int2* ce = (int2*)alloc((size_t)E * 8);  // packed (col, nrm)
    float* dinv = (float*)alloc((size_t)Nn * 4);
    unsigned short* w1hi = (unsigned short*)alloc((size_t)N_FEAT_IN * N_HID * 2);
    unsigned short* w1lo = (unsigned short*)alloc((size_t)N_FEAT_IN * N_HID * 2);
    unsigned short* w2hi = (unsigned short*)alloc((size_t)N_HID * N_OUT * 2);
    unsigned short* w2lo = (unsigned short*)alloc((size_t)N_HID * N_OUT * 2);
    unsigned short* a1hi = (unsigned short*)alloc((size_t)Nn * N_HID * 2);
    unsigned short* a1lo = (unsigned short*)alloc((size_t)Nn * N_HID * 2);
    unsigned short* h = (unsigned short*)alloc((size_t)Nn * N_HID * 2);  // bf16 h1, then h2

    hipMemsetAsync(cnt, 0, (size_t)Nn * 4, stream);
    detect_i64_kernel<<<1, 256, 0, stream>>>((const int*)edges, flag);
    const int eb = (E + 255) / 256;
    count_kernel<<<eb, 256, 0, stream>>>(edges, E, flag, cnt);
    const int nb = (Nn + 255) / 256;
    scan_block_kernel<<<nb, 256, 0, stream>>>(cnt, Nn, rowp, bsum, dinv);
    scan_top_kernel<<<1, 256, 0, stream>>>(bsum, nb, rowp, Nn);
    scan_add_kernel<<<nb, 256, 0, stream>>>(bsum, Nn, rowp, cursor);
    fill_kernel<<<eb, 256, 0, stream>>>(edges, E, flag, dinv, cursor, ce);

    // Weight splits (tiny)
    splitT_kernel<<<(N_FEAT_IN * N_HID + 255) / 256, 256, 0, stream>>>(W1, N_FEAT_IN, N_HID, w1hi, w1lo);
    splitT_kernel<<<(N_HID * N_OUT + 255) / 256, 256, 0, stream>>>(W2, N_HID, N_OUT, w2hi, w2lo);

    // Layer 1: h(bf16) = x(f32, split fused in staging) @ W1 ; a1(split) = relu(Agg(h)+b1)
    dim3 g1(N_HID / 128, (Nn + 127) / 128);
    gemm_mfma_f32a_kernel<<<g1, 256, 0, stream>>>(x, w1hi, w1lo, h, Nn, N_HID, N_FEAT_IN);
    agg_kernel<N_HID, true, true><<<(Nn + 3) / 4, 256, 0, stream>>>(
        h, rowp, ce, dinv, b1, nullptr, a1hi, a1lo, Nn);

    // Layer 2: h2(bf16) = a1 @ W2 (reuse h); out = Agg(h2) + b2
    dim3 g2(N_OUT / 128, (Nn + 127) / 128);
    gemm_mfma_kernel<<<g2, 256, 0, stream>>>(a1hi, a1lo, w2hi, w2lo, h, Nn, N_OUT, N_HID);
    agg_kernel<N_OUT, false, false><<<(Nn + 3) / 4, 256, 0, stream>>>(
        h, rowp, ce, dinv, b2, out, nullptr, nullptr, Nn);
}